// Round 2
// baseline (268.739 us; speedup 1.0000x reference)
//
#include <hip/hip_runtime.h>

#define QSIZE 4194304          // B*D*H*W = 64*64*1024
#define WS_E2_OFF   0          // e2[1024] f32  : sum_d e^2 (numpy-pairwise replica)
#define WS_IND_OFF  4096       // ind[65536] i32
#define WS_PART_OFF 266240     // part[16384] f32

// ---- kernel 0: e2[k] = np.sum(emb**2, axis=1) replicated in f32 (pairwise-8) ----
__global__ void k0_e2(const float* __restrict__ emb, float* __restrict__ e2) {
    #pragma clang fp contract(off)
    int k = blockIdx.x * blockDim.x + threadIdx.x;
    if (k >= 1024) return;
    const float* e = emb + k * 64;
    float r[8];
    #pragma unroll
    for (int j = 0; j < 8; ++j) r[j] = e[j] * e[j];
    #pragma unroll
    for (int i = 8; i < 64; i += 8) {
        #pragma unroll
        for (int j = 0; j < 8; ++j) r[j] = r[j] + e[i + j] * e[i + j];
    }
    e2[k] = ((r[0] + r[1]) + (r[2] + r[3])) + ((r[4] + r[5]) + (r[6] + r[7]));
}

// ---- kernel 1: per row, replicate f32 dist = (x2 + e2[k]) - 2*(x.e_k) and argmin ----
// grid 1024 x 256. Block owns 64 rows (one b); wave w handles codes [w*256, w*256+256).
__launch_bounds__(256)
__global__ void k1_argmin(const float* __restrict__ lat, const float* __restrict__ emb,
                          const float* __restrict__ e2, int* __restrict__ ind) {
    #pragma clang fp contract(off)
    __shared__ float sm1[4][64];
    __shared__ int   sbi[4][64];

    const int tid  = threadIdx.x;
    const int lane = tid & 63;
    const int w    = tid >> 6;
    const int row0 = blockIdx.x * 64;
    const int row  = row0 + lane;
    const int b    = row >> 10;
    const int hw   = row & 1023;

    // x row: coalesced across lanes for each d
    const float* xg = lat + (size_t)b * 65536 + hw;
    float x[64];
    #pragma unroll
    for (int d = 0; d < 64; ++d) x[d] = xg[d * 1024];

    // x2 = numpy pairwise-8 sum of squares (square rounded, then plain adds; contract off)
    float r[8];
    #pragma unroll
    for (int j = 0; j < 8; ++j) r[j] = x[j] * x[j];
    #pragma unroll
    for (int i = 8; i < 64; i += 8) {
        #pragma unroll
        for (int j = 0; j < 8; ++j) r[j] = r[j] + x[i + j] * x[i + j];
    }
    const float x2 = ((r[0] + r[1]) + (r[2] + r[3])) + ((r[4] + r[5]) + (r[6] + r[7]));

    // wave-uniform code chunk -> scalar-load-friendly embedding access
    const int kbase = __builtin_amdgcn_readfirstlane(w) << 8;
    const float* eb = emb + (size_t)kbase * 64;

    float m1 = 3.4e38f;
    int   bi = kbase;
    #pragma unroll 1
    for (int kk = 0; kk < 256; kk += 4) {
        const float* ep = eb + (size_t)kk * 64;
        // sequential FMA chain over d (ascending), one chain per code: sgemm replica
        float c0 = 0.f, c1 = 0.f, c2 = 0.f, c3 = 0.f;
        #pragma unroll
        for (int d = 0; d < 64; ++d) {
            c0 = __builtin_fmaf(x[d], ep[d],       c0);
            c1 = __builtin_fmaf(x[d], ep[d +  64], c1);
            c2 = __builtin_fmaf(x[d], ep[d + 128], c2);
            c3 = __builtin_fmaf(x[d], ep[d + 192], c3);
        }
        const float e20 = e2[kbase + kk + 0];
        const float e21 = e2[kbase + kk + 1];
        const float e22 = e2[kbase + kk + 2];
        const float e23 = e2[kbase + kk + 3];
        // dist = fl(fl(x2 + e2) - 2*xe); 2*c exact (power of two)
        const float t0 = x2 + e20; const float d0v = t0 - 2.0f * c0;
        const float t1 = x2 + e21; const float d1v = t1 - 2.0f * c1;
        const float t2 = x2 + e22; const float d2v = t2 - 2.0f * c2;
        const float t3 = x2 + e23; const float d3v = t3 - 2.0f * c3;
        // strict < in ascending k: np.argmin first-occurrence tie rule
        if (d0v < m1) { m1 = d0v; bi = kbase + kk + 0; }
        if (d1v < m1) { m1 = d1v; bi = kbase + kk + 1; }
        if (d2v < m1) { m1 = d2v; bi = kbase + kk + 2; }
        if (d3v < m1) { m1 = d3v; bi = kbase + kk + 3; }
    }
    sm1[w][lane] = m1;
    sbi[w][lane] = bi;
    __syncthreads();

    // merge 4 chunks in ascending-k order with strict < (keeps earliest index on ties)
    if (w == 0) {
        float M1 = sm1[0][lane];
        int   BI = sbi[0][lane];
        #pragma unroll
        for (int ww = 1; ww < 4; ++ww) {
            const float a = sm1[ww][lane];
            if (a < M1) { M1 = a; BI = sbi[ww][lane]; }
        }
        ind[row] = BI;
    }
}

// ---- kernel 2: q_out = fl(x + fl(q - x)) (straight-through replica) + loss partials ----
__global__ void k2_qout(const float* __restrict__ lat, const float* __restrict__ emb,
                        const int* __restrict__ ind, float* __restrict__ qout,
                        float* __restrict__ part) {
    #pragma clang fp contract(off)
    __shared__ float red[4];
    int g  = blockIdx.x * 256 + threadIdx.x;   // flat [B][D][HW]
    int bb = g >> 16;
    int d  = (g >> 10) & 63;
    int hw = g & 1023;
    int n  = (bb << 10) + hw;
    int id = ind[n];
    float q  = emb[id * 64 + d];
    float xv = lat[g];
    float qmx = q - xv;
    qout[g] = xv + qmx;
    float sq = qmx * qmx;
    #pragma unroll
    for (int off = 32; off > 0; off >>= 1) sq += __shfl_down(sq, off, 64);
    if ((threadIdx.x & 63) == 0) red[threadIdx.x >> 6] = sq;
    __syncthreads();
    if (threadIdx.x == 0) part[blockIdx.x] = (red[0] + red[1]) + (red[2] + red[3]);
}

// ---- kernel 3: finalize losses + indices as float ----
__global__ void k3_final(const float* __restrict__ part, const int* __restrict__ ind,
                         float* __restrict__ out) {
    if (blockIdx.x == 0) {
        __shared__ double red[256];
        double s = 0.0;
        for (int i = threadIdx.x; i < 16384; i += 256) s += (double)part[i];
        red[threadIdx.x] = s;
        __syncthreads();
        for (int st = 128; st > 0; st >>= 1) {
            if (threadIdx.x < st) red[threadIdx.x] += red[threadIdx.x + st];
            __syncthreads();
        }
        if (threadIdx.x == 0) {
            float L = (float)(red[0] / (double)QSIZE);
            out[QSIZE]     = L;   // commitment_loss
            out[QSIZE + 1] = L;   // embedding_loss
        }
    } else {
        int n = (blockIdx.x - 1) * 256 + threadIdx.x;
        out[QSIZE + 2 + n] = (float)ind[n];
    }
}

extern "C" void kernel_launch(void* const* d_in, const int* in_sizes, int n_in,
                              void* d_out, int out_size, void* d_ws, size_t ws_size,
                              hipStream_t stream) {
    const float* lat = (const float*)d_in[0];   // [64,64,32,32] f32
    const float* emb = (const float*)d_in[1];   // [1024,64] f32
    float* out  = (float*)d_out;
    char*  ws   = (char*)d_ws;
    float* e2   = (float*)(ws + WS_E2_OFF);
    int*   ind  = (int*)(ws + WS_IND_OFF);
    float* part = (float*)(ws + WS_PART_OFF);

    hipLaunchKernelGGL(k0_e2,     dim3(4),     dim3(256), 0, stream, emb, e2);
    hipLaunchKernelGGL(k1_argmin, dim3(1024),  dim3(256), 0, stream, lat, emb, e2, ind);
    hipLaunchKernelGGL(k2_qout,   dim3(16384), dim3(256), 0, stream, lat, emb, ind, out, part);
    hipLaunchKernelGGL(k3_final,  dim3(257),   dim3(256), 0, stream, part, ind, out);
}

// Round 3
// 239.202 us; speedup vs baseline: 1.1235x; 1.1235x over previous
//
#include <hip/hip_runtime.h>

#define QSIZE 4194304          // B*D*H*W = 64*64*1024
#define WS_E2_OFF   0          // e2[1024] f32
#define WS_PART_OFF 4096       // part[1024] f32

// ---- kernel 0: e2[k] = np.sum(emb**2, axis=1) replicated in f32 (pairwise-8) ----
__global__ void k0_e2(const float* __restrict__ emb, float* __restrict__ e2) {
    #pragma clang fp contract(off)
    int k = blockIdx.x * blockDim.x + threadIdx.x;
    if (k >= 1024) return;
    const float* e = emb + k * 64;
    float r[8];
    #pragma unroll
    for (int j = 0; j < 8; ++j) r[j] = e[j] * e[j];
    #pragma unroll
    for (int i = 8; i < 64; i += 8) {
        #pragma unroll
        for (int j = 0; j < 8; ++j) r[j] = r[j] + e[i + j] * e[i + j];
    }
    e2[k] = ((r[0] + r[1]) + (r[2] + r[3])) + ((r[4] + r[5]) + (r[6] + r[7]));
}

// ---- kernel 1: argmin (bit-exact f32 replica) + fused q_out/loss/index epilogue ----
// grid 1024 x 256. Block owns rows [blk*64, blk*64+64) (one b).
// Main loop: wave w scans codes [w*256, (w+1)*256); lane = row-within-block.
__launch_bounds__(256, 4)
__global__ void k1_argmin(const float* __restrict__ lat, const float* __restrict__ emb,
                          const float* __restrict__ e2, float* __restrict__ out,
                          float* __restrict__ part) {
    #pragma clang fp contract(off)
    __shared__ float sm1[4][64];
    __shared__ int   sbi[4][64];
    __shared__ int   sbiF[64];
    __shared__ float red[4];

    const int tid  = threadIdx.x;
    const int lane = tid & 63;
    const int w    = tid >> 6;
    const int row0 = blockIdx.x * 64;
    const int row  = row0 + lane;
    const int b    = row >> 10;
    const int hw   = row & 1023;

    // x row: coalesced across lanes for each d
    const float* xg = lat + (size_t)b * 65536 + hw;
    float x[64];
    #pragma unroll
    for (int d = 0; d < 64; ++d) x[d] = xg[d * 1024];
    // Pin x in VGPRs: opaque to the compiler -> cannot rematerialize the loads.
    #pragma unroll
    for (int d = 0; d < 64; ++d) asm volatile("" : "+v"(x[d]));

    // x2 = numpy pairwise-8 sum of squares (bit-exact replica)
    float r[8];
    #pragma unroll
    for (int j = 0; j < 8; ++j) r[j] = x[j] * x[j];
    #pragma unroll
    for (int i = 8; i < 64; i += 8) {
        #pragma unroll
        for (int j = 0; j < 8; ++j) r[j] = r[j] + x[i + j] * x[i + j];
    }
    const float x2 = ((r[0] + r[1]) + (r[2] + r[3])) + ((r[4] + r[5]) + (r[6] + r[7]));

    // wave-uniform code chunk -> scalar (SGPR) embedding loads
    const int kbase = __builtin_amdgcn_readfirstlane(w) << 8;
    const float* eb = emb + (size_t)kbase * 64;

    float m1 = 3.4e38f;
    int   bi = kbase;
    #pragma unroll 1
    for (int kk = 0; kk < 256; kk += 4) {
        const float* ep = eb + (size_t)kk * 64;
        float c0 = 0.f, c1 = 0.f, c2 = 0.f, c3 = 0.f;
        #pragma unroll
        for (int d = 0; d < 64; ++d) {
            c0 = __builtin_fmaf(x[d], ep[d],       c0);
            c1 = __builtin_fmaf(x[d], ep[d +  64], c1);
            c2 = __builtin_fmaf(x[d], ep[d + 128], c2);
            c3 = __builtin_fmaf(x[d], ep[d + 192], c3);
        }
        const float e20 = e2[kbase + kk + 0];
        const float e21 = e2[kbase + kk + 1];
        const float e22 = e2[kbase + kk + 2];
        const float e23 = e2[kbase + kk + 3];
        const float t0 = x2 + e20; const float d0v = t0 - 2.0f * c0;
        const float t1 = x2 + e21; const float d1v = t1 - 2.0f * c1;
        const float t2 = x2 + e22; const float d2v = t2 - 2.0f * c2;
        const float t3 = x2 + e23; const float d3v = t3 - 2.0f * c3;
        if (d0v < m1) { m1 = d0v; bi = kbase + kk + 0; }
        if (d1v < m1) { m1 = d1v; bi = kbase + kk + 1; }
        if (d2v < m1) { m1 = d2v; bi = kbase + kk + 2; }
        if (d3v < m1) { m1 = d3v; bi = kbase + kk + 3; }
    }
    sm1[w][lane] = m1;
    sbi[w][lane] = bi;
    __syncthreads();

    // wave 0: merge 4 chunks (ascending k, strict < keeps first index on ties)
    if (w == 0) {
        float M1 = sm1[0][lane];
        int   BI = sbi[0][lane];
        #pragma unroll
        for (int ww = 1; ww < 4; ++ww) {
            const float a = sm1[ww][lane];
            if (a < M1) { M1 = a; BI = sbi[ww][lane]; }
        }
        sbiF[lane] = BI;
        out[QSIZE + 2 + row] = (float)BI;   // encoding index as float, coalesced
    }
    __syncthreads();

    // fused epilogue: wave w writes d in [w*16, w*16+16) for all 64 rows.
    // Thread (w,lane) handles its own row (=lane); x slice reloaded (L1-hot).
    {
        const int BI = sbiF[lane];
        const float* er = emb + BI * 64 + w * 16;    // 64B-aligned per-lane gather
        float sq = 0.f;
        #pragma unroll
        for (int j4 = 0; j4 < 4; ++j4) {
            const float4 q4 = *(const float4*)(er + j4 * 4);
            #pragma unroll
            for (int j2 = 0; j2 < 4; ++j2) {
                const int d = w * 16 + j4 * 4 + j2;
                const float xv  = xg[d * 1024];
                const float qv  = (&q4.x)[j2];
                const float qmx = qv - xv;
                out[(size_t)b * 65536 + d * 1024 + hw] = xv + qmx;  // straight-through
                sq = __builtin_fmaf(qmx, qmx, sq);
            }
        }
        #pragma unroll
        for (int off = 32; off > 0; off >>= 1) sq += __shfl_down(sq, off, 64);
        if (lane == 0) red[w] = sq;
    }
    __syncthreads();
    if (tid == 0) part[blockIdx.x] = (red[0] + red[1]) + (red[2] + red[3]);
}

// ---- kernel 3: finalize losses (sum 1024 block partials) ----
__global__ void k3_final(const float* __restrict__ part, float* __restrict__ out) {
    __shared__ double red[256];
    double s = 0.0;
    for (int i = threadIdx.x; i < 1024; i += 256) s += (double)part[i];
    red[threadIdx.x] = s;
    __syncthreads();
    for (int st = 128; st > 0; st >>= 1) {
        if (threadIdx.x < st) red[threadIdx.x] += red[threadIdx.x + st];
        __syncthreads();
    }
    if (threadIdx.x == 0) {
        float L = (float)(red[0] / (double)QSIZE);
        out[QSIZE]     = L;   // commitment_loss
        out[QSIZE + 1] = L;   // embedding_loss
    }
}

extern "C" void kernel_launch(void* const* d_in, const int* in_sizes, int n_in,
                              void* d_out, int out_size, void* d_ws, size_t ws_size,
                              hipStream_t stream) {
    const float* lat = (const float*)d_in[0];   // [64,64,32,32] f32
    const float* emb = (const float*)d_in[1];   // [1024,64] f32
    float* out  = (float*)d_out;
    char*  ws   = (char*)d_ws;
    float* e2   = (float*)(ws + WS_E2_OFF);
    float* part = (float*)(ws + WS_PART_OFF);

    hipLaunchKernelGGL(k0_e2,     dim3(4),    dim3(256), 0, stream, emb, e2);
    hipLaunchKernelGGL(k1_argmin, dim3(1024), dim3(256), 0, stream, lat, emb, e2, out, part);
    hipLaunchKernelGGL(k3_final,  dim3(1),    dim3(256), 0, stream, part, out);
}

// Round 4
// 186.571 us; speedup vs baseline: 1.4404x; 1.2821x over previous
//
#include <hip/hip_runtime.h>

#define QSIZE 4194304          // B*D*H*W = 64*64*1024
#define WS_E2_OFF   0          // e2[1024] f32
#define WS_ET_OFF   4096       // embT[64][1024] f32 = 262144 B
#define WS_PART_OFF 266240     // part[1024] f32

// ---- kernel 0a: e2[k] = np.sum(emb**2, axis=1) replicated in f32 (pairwise-8) ----
__global__ void k0_e2(const float* __restrict__ emb, float* __restrict__ e2) {
    #pragma clang fp contract(off)
    int k = blockIdx.x * blockDim.x + threadIdx.x;
    if (k >= 1024) return;
    const float* e = emb + k * 64;
    float r[8];
    #pragma unroll
    for (int j = 0; j < 8; ++j) r[j] = e[j] * e[j];
    #pragma unroll
    for (int i = 8; i < 64; i += 8) {
        #pragma unroll
        for (int j = 0; j < 8; ++j) r[j] = r[j] + e[i + j] * e[i + j];
    }
    e2[k] = ((r[0] + r[1]) + (r[2] + r[3])) + ((r[4] + r[5]) + (r[6] + r[7]));
}

// ---- kernel 0b: embT[d][k] = emb[k][d] (64KB table, L2-resident) ----
__global__ void k0_tr(const float* __restrict__ emb, float* __restrict__ embT) {
    int g = blockIdx.x * 256 + threadIdx.x;   // 0..65535
    int d = g >> 10, k = g & 1023;
    embT[g] = emb[k * 64 + d];
}

// ---- kernel 1: argmin (bit-exact f32 replica) + fused q_out/loss/index epilogue ----
// grid 1024 x 256. Block owns rows [blk*64, blk*64+64) (one b).
// Wave w scans codes [w*256,(w+1)*256) in groups of 16; lane = row-within-block.
// x lives in LDS (transposed float2); e streams through SGPRs from embT.
__launch_bounds__(256, 4)
__global__ void k1_argmin(const float* __restrict__ lat, const float* __restrict__ embT,
                          const float* __restrict__ e2t, const float* __restrict__ emb,
                          float* __restrict__ out, float* __restrict__ part) {
    #pragma clang fp contract(off)
    __shared__ float2 xs2[32][64];   // [d/2][row] : x[2dd..2dd+1] of each row, 16 KB
    __shared__ float sm1[4][64];
    __shared__ int   sbi[4][64];
    __shared__ int   sbiF[64];
    __shared__ float red[4];

    const int tid  = threadIdx.x;
    const int lane = tid & 63;
    const int w    = tid >> 6;
    const int row0 = blockIdx.x * 64;
    const int row  = row0 + lane;
    const int b    = row >> 10;
    const int hw   = row & 1023;

    // ---- stage x into LDS (coalesced global reads, conflict-free LDS writes) ----
    {
        const int hwb = row0 & 1023;
        const float* latb = lat + (size_t)b * 65536 + hwb;
        #pragma unroll
        for (int i = 0; i < 16; ++i) {
            const int idx = i * 256 + tid;          // 0..4095
            const int d = idx >> 6, r = idx & 63;
            const float v = latb[d * 1024 + r];
            ((float*)&xs2[d >> 1][r])[d & 1] = v;
        }
    }
    __syncthreads();

    // ---- x2 = numpy pairwise-8 sum of squares for own row (redundant per wave) ----
    float x2;
    {
        float r[8];
        #pragma unroll
        for (int j = 0; j < 8; ++j) {
            const float v = ((const float*)&xs2[j >> 1][lane])[j & 1];
            r[j] = v * v;
        }
        #pragma unroll
        for (int i = 8; i < 64; i += 8) {
            #pragma unroll
            for (int j = 0; j < 8; ++j) {
                const float v = ((const float*)&xs2[(i + j) >> 1][lane])[(i + j) & 1];
                r[j] = r[j] + v * v;
            }
        }
        x2 = ((r[0] + r[1]) + (r[2] + r[3])) + ((r[4] + r[5]) + (r[6] + r[7]));
    }

    // ---- main loop: 16 codes at a time, e via wave-uniform scalar loads ----
    const int kbase = __builtin_amdgcn_readfirstlane(w) << 8;
    float m1 = 3.4e38f;
    int   bi = kbase;
    #pragma unroll 1
    for (int g = 0; g < 16; ++g) {
        const int k0 = kbase + (g << 4);
        const float* __restrict__ ed  = embT + k0;   // column block [*, k0..k0+15]
        const float* __restrict__ e2g = e2t + k0;
        float c[16];
        #pragma unroll
        for (int j = 0; j < 16; ++j) c[j] = 0.f;
        #pragma unroll 2
        for (int dd = 0; dd < 32; ++dd) {
            const float2 xv = xs2[dd][lane];
            const float* e0 = ed + (dd << 11);       // row 2dd of embT
            #pragma unroll
            for (int j = 0; j < 16; ++j) c[j] = __builtin_fmaf(xv.x, e0[j], c[j]);
            const float* e1 = e0 + 1024;             // row 2dd+1
            #pragma unroll
            for (int j = 0; j < 16; ++j) c[j] = __builtin_fmaf(xv.y, e1[j], c[j]);
        }
        #pragma unroll
        for (int j = 0; j < 16; ++j) {
            const float t  = x2 + e2g[j];
            const float dv = t - 2.0f * c[j];        // 2*c exact (power of two)
            if (dv < m1) { m1 = dv; bi = k0 + j; }   // strict <, ascending k
        }
    }
    sm1[w][lane] = m1;
    sbi[w][lane] = bi;
    __syncthreads();

    // ---- wave 0: merge 4 chunks (ascending k, strict < keeps first index) ----
    if (w == 0) {
        float M1 = sm1[0][lane];
        int   BI = sbi[0][lane];
        #pragma unroll
        for (int ww = 1; ww < 4; ++ww) {
            const float a = sm1[ww][lane];
            if (a < M1) { M1 = a; BI = sbi[ww][lane]; }
        }
        sbiF[lane] = BI;
        out[QSIZE + 2 + row] = (float)BI;            // index as float, coalesced
    }
    __syncthreads();

    // ---- fused epilogue: wave w writes d in [w*16, w*16+16) for all rows ----
    {
        const float* xg = lat + (size_t)b * 65536 + hw;
        const int BI = sbiF[lane];
        const float* er = emb + BI * 64 + w * 16;    // 64B-aligned per-lane gather
        float sq = 0.f;
        #pragma unroll
        for (int j4 = 0; j4 < 4; ++j4) {
            const float4 q4 = *(const float4*)(er + j4 * 4);
            #pragma unroll
            for (int j2 = 0; j2 < 4; ++j2) {
                const int d = w * 16 + j4 * 4 + j2;
                const float xv  = xg[d * 1024];
                const float qv  = (&q4.x)[j2];
                const float qmx = qv - xv;
                out[(size_t)b * 65536 + d * 1024 + hw] = xv + qmx;  // straight-through
                sq = __builtin_fmaf(qmx, qmx, sq);
            }
        }
        #pragma unroll
        for (int off = 32; off > 0; off >>= 1) sq += __shfl_down(sq, off, 64);
        if (lane == 0) red[w] = sq;
    }
    __syncthreads();
    if (tid == 0) part[blockIdx.x] = (red[0] + red[1]) + (red[2] + red[3]);
}

// ---- kernel 3: finalize losses (sum 1024 block partials) ----
__global__ void k3_final(const float* __restrict__ part, float* __restrict__ out) {
    __shared__ double red[256];
    double s = 0.0;
    for (int i = threadIdx.x; i < 1024; i += 256) s += (double)part[i];
    red[threadIdx.x] = s;
    __syncthreads();
    for (int st = 128; st > 0; st >>= 1) {
        if (threadIdx.x < st) red[threadIdx.x] += red[threadIdx.x + st];
        __syncthreads();
    }
    if (threadIdx.x == 0) {
        float L = (float)(red[0] / (double)QSIZE);
        out[QSIZE]     = L;   // commitment_loss
        out[QSIZE + 1] = L;   // embedding_loss
    }
}

extern "C" void kernel_launch(void* const* d_in, const int* in_sizes, int n_in,
                              void* d_out, int out_size, void* d_ws, size_t ws_size,
                              hipStream_t stream) {
    const float* lat = (const float*)d_in[0];   // [64,64,32,32] f32
    const float* emb = (const float*)d_in[1];   // [1024,64] f32
    float* out  = (float*)d_out;
    char*  ws   = (char*)d_ws;
    float* e2t  = (float*)(ws + WS_E2_OFF);
    float* embT = (float*)(ws + WS_ET_OFF);
    float* part = (float*)(ws + WS_PART_OFF);

    hipLaunchKernelGGL(k0_e2,     dim3(4),    dim3(256), 0, stream, emb, e2t);
    hipLaunchKernelGGL(k0_tr,     dim3(256),  dim3(256), 0, stream, emb, embT);
    hipLaunchKernelGGL(k1_argmin, dim3(1024), dim3(256), 0, stream, lat, embT, e2t, emb, out, part);
    hipLaunchKernelGGL(k3_final,  dim3(1),    dim3(256), 0, stream, part, out);
}